// Round 1
// baseline (565.043 us; speedup 1.0000x reference)
//
#include <hip/hip_runtime.h>

#define N_NODES 32768
#define EMBED   512
#define NNZ_TOT 1048576
#define LN_EPS  1e-5f

typedef __attribute__((ext_vector_type(8))) short bf16x8;
typedef __attribute__((ext_vector_type(4))) float f32x4;
typedef __attribute__((ext_vector_type(4))) unsigned int u32x4;

__device__ __forceinline__ unsigned short f2bf(float x) {
    unsigned int u = __float_as_uint(x);
    unsigned int r = u + 0x7fffu + ((u >> 16) & 1u);   // RNE
    return (unsigned short)(r >> 16);
}
__device__ __forceinline__ unsigned int pk2(float a, float b) {
    return (unsigned int)f2bf(a) | ((unsigned int)f2bf(b) << 16);
}

// ---------------- zero scratch ints ----------------
__global__ void zero_ints(int* __restrict__ p, int n) {
    int i = blockIdx.x * blockDim.x + threadIdx.x;
    if (i < n) p[i] = 0;
}

// ---------------- W [k][n] fp32 -> Wt [n][k] bf16 ----------------
__global__ __launch_bounds__(256) void wt_kernel(
    const float* __restrict__ W, unsigned short* __restrict__ Wt)
{
    __shared__ float tile[32][33];
    const int tx = threadIdx.x & 31, ty = threadIdx.x >> 5;  // ty 0..7
    const int kb = blockIdx.y * 32, nb = blockIdx.x * 32;
#pragma unroll
    for (int i = 0; i < 32; i += 8)
        tile[ty + i][tx] = W[(long)(kb + ty + i) * EMBED + nb + tx];
    __syncthreads();
#pragma unroll
    for (int i = 0; i < 32; i += 8)
        Wt[(long)(nb + ty + i) * EMBED + kb + tx] = f2bf(tile[tx][ty + i]);
}

// ---------------- gather + bf16 MFMA GEMM: support = bf16(emb[uids]) @ bf16(W) ----------------
__global__ __launch_bounds__(256) void gemm_mfma(
    const int* __restrict__ uids, const float* __restrict__ emb,
    const unsigned short* __restrict__ Wt, unsigned short* __restrict__ support)
{
    __shared__ unsigned short As[128][40];
    __shared__ unsigned short Bs[128][40];

    const int t  = threadIdx.x;
    const int m0 = blockIdx.y * 128;
    const int n0 = blockIdx.x * 128;

    const int wave = t >> 6;
    const int lane = t & 63;
    const int wm   = (wave & 1) * 64;
    const int wn   = (wave >> 1) * 64;
    const int l16  = lane & 15;
    const int quad = lane >> 4;

    const int srow  = t >> 1;
    const int shalf = (t & 1) * 16;
    const int uid   = uids[m0 + srow];
    const float* arow = emb + (long)uid * EMBED + shalf;
    const unsigned short* brow = Wt + (long)(n0 + srow) * EMBED + shalf;

    f32x4 acc[4][4] = {};

    for (int k0 = 0; k0 < EMBED; k0 += 32) {
        const float4* ap = (const float4*)(arow + k0);
        float4 v0 = ap[0], v1 = ap[1], v2 = ap[2], v3 = ap[3];
        u32x4 lo, hi;
        lo.x = pk2(v0.x, v0.y); lo.y = pk2(v0.z, v0.w);
        lo.z = pk2(v1.x, v1.y); lo.w = pk2(v1.z, v1.w);
        hi.x = pk2(v2.x, v2.y); hi.y = pk2(v2.z, v2.w);
        hi.z = pk2(v3.x, v3.y); hi.w = pk2(v3.z, v3.w);
        *(u32x4*)&As[srow][shalf]     = lo;
        *(u32x4*)&As[srow][shalf + 8] = hi;
        const u32x4* bp = (const u32x4*)(brow + k0);
        *(u32x4*)&Bs[srow][shalf]     = bp[0];
        *(u32x4*)&Bs[srow][shalf + 8] = bp[1];
        __syncthreads();

        bf16x8 af[4], bfr[4];
#pragma unroll
        for (int i = 0; i < 4; ++i)
            af[i] = *(const bf16x8*)&As[wm + i * 16 + l16][quad * 8];
#pragma unroll
        for (int j = 0; j < 4; ++j)
            bfr[j] = *(const bf16x8*)&Bs[wn + j * 16 + l16][quad * 8];
#pragma unroll
        for (int i = 0; i < 4; ++i)
#pragma unroll
            for (int j = 0; j < 4; ++j)
                acc[i][j] = __builtin_amdgcn_mfma_f32_16x16x32_bf16(af[i], bfr[j], acc[i][j], 0, 0, 0);
        __syncthreads();
    }

#pragma unroll
    for (int i = 0; i < 4; ++i) {
#pragma unroll
        for (int j = 0; j < 4; ++j) {
            const int col = n0 + wn + j * 16 + l16;
#pragma unroll
            for (int r = 0; r < 4; ++r) {
                const int row = m0 + wm + i * 16 + quad * 4 + r;
                support[(long)row * EMBED + col] = f2bf(acc[i][j][r]);
            }
        }
    }
}

// ---------------- CSR build ----------------
__global__ void hist_kernel(const int* __restrict__ adj_row, int* __restrict__ counts) {
    int i = blockIdx.x * blockDim.x + threadIdx.x;
    if (i < NNZ_TOT) atomicAdd(&counts[adj_row[i]], 1);
}

__global__ __launch_bounds__(1024) void scan_kernel(
    const int* __restrict__ counts, int* __restrict__ row_start)
{
    __shared__ int ssum[1024];
    const int t = threadIdx.x;
    const int base = t * 32;
    int loc[32];
    int run = 0;
#pragma unroll
    for (int i = 0; i < 32; ++i) {
        int c = counts[base + i];
        loc[i] = run;
        run += c;
    }
    ssum[t] = run;
    __syncthreads();
    for (int off = 1; off < 1024; off <<= 1) {
        int v = (t >= off) ? ssum[t - off] : 0;
        __syncthreads();
        ssum[t] += v;
        __syncthreads();
    }
    int prefix = (t > 0) ? ssum[t - 1] : 0;
#pragma unroll
    for (int i = 0; i < 32; ++i) row_start[base + i] = prefix + loc[i];
    if (t == 1023) row_start[N_NODES] = ssum[1023];
}

__global__ void scatter_kernel(
    const int* __restrict__ adj_row, const int* __restrict__ adj_col,
    const float* __restrict__ adj_vals, const int* __restrict__ row_start,
    int* __restrict__ cursor, int2* __restrict__ sc)
{
    int i = blockIdx.x * blockDim.x + threadIdx.x;
    if (i < NNZ_TOT) {
        int r = adj_row[i];
        int pos = atomicAdd(&cursor[r], 1);
        sc[row_start[r] + pos] = make_int2(adj_col[i], __float_as_int(adj_vals[i]));
    }
}

// ---------------- aggregation v3: one wave per row, 8-deep gather pipeline ----------------
// Each wave owns one full row (64 lanes x 8 dims = 512). Per iteration it batches
// 8 edges: 8 wave-uniform sc loads (scalarized via readfirstlane) feeding 8
// independent 1KB gathers in flight. No LDS, no __syncthreads; LN is a pure
// wave shfl_xor reduction.
__global__ __launch_bounds__(256) void agg_ln_v3(
    const int* __restrict__ row_start, const int2* __restrict__ sc,
    const unsigned short* __restrict__ support,
    const float* __restrict__ bias, const float* __restrict__ gamma,
    const float* __restrict__ beta, float* __restrict__ out)
{
    const int t = threadIdx.x;
    const int n = __builtin_amdgcn_readfirstlane((blockIdx.x << 2) + (t >> 6));
    const int l = t & 63;
    const int s = row_start[n];
    const int e = row_start[n + 1];

    const unsigned short* supp_l = support + l * 8;   // lane owns dims [8l, 8l+8)

    float acc[8] = {};
    for (int i = s; i < e; i += 8) {
        int   col[8];
        float val[8];
#pragma unroll
        for (int j = 0; j < 8; ++j) {
            const bool ok = (i + j) < e;              // wave-uniform
            int2 p = sc[ok ? (i + j) : s];
            col[j] = __builtin_amdgcn_readfirstlane(p.x);
            val[j] = __uint_as_float(
                (unsigned)__builtin_amdgcn_readfirstlane(ok ? p.y : 0));
        }
        u32x4 u[8];
#pragma unroll
        for (int j = 0; j < 8; ++j)
            u[j] = *(const u32x4*)(supp_l + col[j] * EMBED);
#pragma unroll
        for (int j = 0; j < 8; ++j) {
            const float v = val[j];
#pragma unroll
            for (int q = 0; q < 4; ++q) {
                unsigned int a = u[j][q];
                acc[2 * q]     = fmaf(v, __uint_as_float(a << 16), acc[2 * q]);
                acc[2 * q + 1] = fmaf(v, __uint_as_float(a & 0xffff0000u), acc[2 * q + 1]);
            }
        }
    }

    // bias + LayerNorm, fully within the wave
    const int d = l * 8;
    const float4 b0 = *(const float4*)(bias + d);
    const float4 b1 = *(const float4*)(bias + d + 4);
    acc[0] += b0.x; acc[1] += b0.y; acc[2] += b0.z; acc[3] += b0.w;
    acc[4] += b1.x; acc[5] += b1.y; acc[6] += b1.z; acc[7] += b1.w;

    float s1 = 0.f, s2 = 0.f;
#pragma unroll
    for (int j = 0; j < 8; ++j) { s1 += acc[j]; s2 = fmaf(acc[j], acc[j], s2); }
#pragma unroll
    for (int off = 32; off > 0; off >>= 1) {
        s1 += __shfl_xor(s1, off, 64);
        s2 += __shfl_xor(s2, off, 64);
    }
    const float mean = s1 * (1.f / 512.f);
    const float var  = s2 * (1.f / 512.f) - mean * mean;
    const float rstd = rsqrtf(var + LN_EPS);

    const float4 g0  = *(const float4*)(gamma + d);
    const float4 g1  = *(const float4*)(gamma + d + 4);
    const float4 be0 = *(const float4*)(beta + d);
    const float4 be1 = *(const float4*)(beta + d + 4);
    float4 o0, o1;
    o0.x = (acc[0] - mean) * rstd * g0.x + be0.x;
    o0.y = (acc[1] - mean) * rstd * g0.y + be0.y;
    o0.z = (acc[2] - mean) * rstd * g0.z + be0.z;
    o0.w = (acc[3] - mean) * rstd * g0.w + be0.w;
    o1.x = (acc[4] - mean) * rstd * g1.x + be1.x;
    o1.y = (acc[5] - mean) * rstd * g1.y + be1.y;
    o1.z = (acc[6] - mean) * rstd * g1.z + be1.z;
    o1.w = (acc[7] - mean) * rstd * g1.w + be1.w;

    float* orow = out + (long)n * EMBED + d;
    *(float4*)orow       = o0;
    *(float4*)(orow + 4) = o1;
}

// ---------------- launch ----------------
extern "C" void kernel_launch(void* const* d_in, const int* in_sizes, int n_in,
                              void* d_out, int out_size, void* d_ws, size_t ws_size,
                              hipStream_t stream)
{
    const int*   user_ids = (const int*)  d_in[0];
    const int*   adj_row  = (const int*)  d_in[1];
    const int*   adj_col  = (const int*)  d_in[2];
    const float* adj_vals = (const float*)d_in[3];
    const float* emb      = (const float*)d_in[4];
    const float* W        = (const float*)d_in[5];
    const float* bias     = (const float*)d_in[6];
    const float* gamma    = (const float*)d_in[7];
    const float* beta     = (const float*)d_in[8];
    float* out = (float*)d_out;

    char* ws = (char*)d_ws;
    size_t off = 0;
    unsigned short* support = (unsigned short*)(ws + off); off += (size_t)N_NODES * EMBED * 2; // 32 MB
    unsigned short* Wt      = (unsigned short*)(ws + off); off += (size_t)EMBED * EMBED * 2;   // 512 KB
    int2*  sc        = (int2*) (ws + off); off += (size_t)NNZ_TOT * 8;                         // 8 MB
    int*   row_start = (int*)  (ws + off); off += (size_t)(N_NODES + 4) * 4;
    int*   counts    = (int*)  (ws + off); off += (size_t)N_NODES * 4;
    int*   cursor    = (int*)  (ws + off); off += (size_t)N_NODES * 4;   // contiguous with counts
    (void)off; (void)ws_size; (void)in_sizes; (void)n_in; (void)out_size;

    zero_ints<<<(2 * N_NODES + 255) / 256, 256, 0, stream>>>(counts, 2 * N_NODES);

    wt_kernel<<<dim3(16, 16), 256, 0, stream>>>(W, Wt);

    gemm_mfma<<<dim3(EMBED / 128, N_NODES / 128), 256, 0, stream>>>(user_ids, emb, Wt, support);

    hist_kernel<<<NNZ_TOT / 256, 256, 0, stream>>>(adj_row, counts);
    scan_kernel<<<1, 1024, 0, stream>>>(counts, row_start);
    scatter_kernel<<<NNZ_TOT / 256, 256, 0, stream>>>(adj_row, adj_col, adj_vals,
                                                      row_start, cursor, sc);

    agg_ln_v3<<<N_NODES / 4, 256, 0, stream>>>(row_start, sc, support,
                                               bias, gamma, beta, out);
}